// Round 14
// baseline (435.575 us; speedup 1.0000x reference)
//
#include <hip/hip_runtime.h>
#include <hip/hip_bf16.h>
#include <cstdint>
#include <cstddef>

#define D_MODEL 1024
#define N_EXP   8
#define HID     4096
#define T_TOK   4096          // B*S
#define NPAIR   (T_TOK * 2)   // top-2
#define WSLOTS  72            // max m-tiles total: 8192/128 + 7 = 71
#define FFN1B   (32 * WSLOTS) // 2304 ffn1 blocks
#define CVT2B   2048          // W2 cvt blocks (8 x 32 x 8)
#define SCATB   32            // scatter blocks (NPAIR/256)
#define CVT1B   2048          // W1 cvt blocks (32 x 8 x 8)

// ---------------- workspace layout (bytes) ----------------
#define WS_COUNTS   0
#define WS_CURSOR   32
#define WS_OFFSETS  64
#define WS_TOKE     128                       // tok_e[T][2] int
#define WS_TOKG     32896                     // tok_g[T][2] float
#define WS_LTOK     65664                     // list_tok[NPAIR] int
#define WS_LGATE    98432                     // list_gate[NPAIR] float
#define WS_XB       131328                    // xb[T][1024] bf16        (8 MB)
#define WS_WB       (WS_XB + 8388608)         // W1t bf16                (64 MB)
#define WS_H        (WS_WB + 67108864)        // H[NPAIR][4096] bf16     (64 MB)
#define WS_W2       (WS_H + 67108864)         // W2t bf16 (if ws allows) (64 MB)
#define WS_NEEDED   ((size_t)WS_W2 + 67108864)

typedef __attribute__((ext_vector_type(8))) short bf16x8;
typedef __attribute__((ext_vector_type(4))) float f32x4;
typedef __attribute__((ext_vector_type(8))) unsigned short u16x8;
typedef unsigned short u16;

__device__ __forceinline__ u16 f2bf(float f) {
    unsigned u = __float_as_uint(f);
    u += 0x7FFFu + ((u >> 16) & 1u);          // RNE
    return (u16)(u >> 16);
}

__device__ __forceinline__ void glds16(const void* g, void* l) {
    __builtin_amdgcn_global_load_lds(
        (const __attribute__((address_space(1))) void*)g,
        (__attribute__((address_space(3))) void*)l, 16, 0, 0);
}

// Swizzled-stage chunk map (validated r3/r6: conflicts 0, bit-exact output).
__device__ __forceinline__ void chunk_map(int c, int& row, int& kc) {
    const int line = c >> 3, c8 = c & 7, u = c8 ^ (line & 7);
    row = line * 2 + (u >> 2);
    kc  = (u & 3) * 8;                        // ushort offset in 32-wide K window
}

// compact worklist: slot w -> (expert, m_tile). uniform per block.
__device__ __forceinline__ bool work_map(const int* counts, int w,
                                         int& e, int& m_t) {
    int tot = 0; e = -1; m_t = 0;
    #pragma unroll
    for (int i = 0; i < N_EXP; ++i) {
        const int tl = (counts[i] + 127) >> 7;
        if (e < 0 && w < tot + tl) { e = i; m_t = w - tot; }
        tot += tl;
    }
    return e >= 0;
}

// ---------------------------------------------------------------------------
// Transpose+convert tile body (v3, validated r12/r13): f32 [R][C] -> bf16
// [C][R], 128x128 tile. s = u16[128*134] LDS scratch.
// ---------------------------------------------------------------------------
__device__ __forceinline__ void cvt_tile(
    const float* __restrict__ in, u16* __restrict__ outp, int R, int C,
    int bx, int by, int bz, u16* s)
{
    const size_t esz = (size_t)R * C;
    const float* ine = in + (size_t)bz * esz;
    u16* oute = outp + (size_t)bz * esz;
    const int c0 = bx * 128, r0 = by * 128;
    const int tid = threadIdx.x;

    #pragma unroll
    for (int p = 0; p < 16; ++p) {
        const int idx = p * 256 + tid;
        const int row = idx >> 5, c4 = (idx & 31) * 4;
        const float4 v = *(const float4*)(ine + (size_t)(r0 + row) * C + c0 + c4);
        ushort2 lo, hi;
        lo.x = f2bf(v.x); lo.y = f2bf(v.y);
        hi.x = f2bf(v.z); hi.y = f2bf(v.w);
        *(ushort2*)(s + row * 134 + c4)     = lo;
        *(ushort2*)(s + row * 134 + c4 + 2) = hi;
    }
    __syncthreads();

    #pragma unroll
    for (int p = 0; p < 8; ++p) {
        const int idx = p * 256 + tid;
        const int col = idx >> 4, r8 = (idx & 15) * 8;
        u16x8 o;
        #pragma unroll
        for (int i = 0; i < 8; ++i) o[i] = s[(r8 + i) * 134 + col];
        *(u16x8*)(oute + (size_t)(c0 + col) * R + r0 + r8) = o;
    }
}

// standalone cvt kernel (fallback path for W2)
__global__ __launch_bounds__(256) void k_cvtT(
    const float* __restrict__ in, u16* __restrict__ outp, int R, int C)
{
    __shared__ __align__(16) u16 s[128 * 134];
    cvt_tile(in, outp, R, C, blockIdx.x, blockIdx.y, blockIdx.z, s);
}

// ---------------------------------------------------------------------------
// Router (r12-validated: small LDS, fused x -> bf16)
// ---------------------------------------------------------------------------
__global__ __launch_bounds__(256) void k_router(
    const float* __restrict__ x, const float* __restrict__ noise,
    const float* __restrict__ Wr, const float* __restrict__ br,
    const float* __restrict__ Wn, const float* __restrict__ bn,
    int* __restrict__ counts, int* __restrict__ tok_e, float* __restrict__ tok_g,
    u16* __restrict__ xb)
{
    const int t   = blockIdx.x;
    const int tid = threadIdx.x;
    const int e   = tid & 7;
    const int g   = tid >> 3;
    const float* xr = x + (size_t)t * D_MODEL;

    {
        const float4 v4 = *(const float4*)(xr + tid * 4);
        ushort4 o;
        o.x = f2bf(v4.x); o.y = f2bf(v4.y); o.z = f2bf(v4.z); o.w = f2bf(v4.w);
        *(ushort4*)(xb + (size_t)t * D_MODEL + tid * 4) = o;
    }

    float ar = 0.f, an = 0.f;
    const int ibase = g * 32;
    #pragma unroll 8
    for (int j = 0; j < 32; ++j) {
        const int i = ibase + j;
        const float xv = xr[i];
        ar = fmaf(xv, Wr[i * 8 + e], ar);
        an = fmaf(xv, Wn[i * 8 + e], an);
    }

    __shared__ float sR[256], sN[256];
    sR[tid] = ar; sN[tid] = an;
    __syncthreads();
    for (int off = 128; off >= 8; off >>= 1) {
        if (tid < off) { sR[tid] += sR[tid + off]; sN[tid] += sN[tid + off]; }
        __syncthreads();
    }

    __shared__ float lg[8];
    if (tid < 8) {
        const float z  = sN[tid] + bn[tid];
        const float sp = fmaxf(z, 0.f) + log1pf(expf(-fabsf(z)));
        lg[tid] = sR[tid] + br[tid] + sp * noise[t * 8 + tid];
    }
    __syncthreads();

    if (tid == 0) {
        float v0 = -INFINITY, v1 = -INFINITY;
        int   i0 = 0,         i1 = 0;
        #pragma unroll
        for (int ee = 0; ee < 8; ++ee) {
            const float v = lg[ee];
            if (v > v0)      { v1 = v0; i1 = i0; v0 = v; i0 = ee; }
            else if (v > v1) { v1 = v;  i1 = ee; }
        }
        const float ew  = expf(v1 - v0);
        const float inv = 1.f / (1.f + ew);
        tok_e[t * 2 + 0] = i0;
        tok_e[t * 2 + 1] = i1;
        tok_g[t * 2 + 0] = inv;
        tok_g[t * 2 + 1] = ew * inv;
        atomicAdd(&counts[i0], 1);
        atomicAdd(&counts[i1], 1);
    }
}

__global__ void k_prefix(const int* __restrict__ counts, int* __restrict__ offsets)
{
    if (threadIdx.x == 0 && blockIdx.x == 0) {
        int acc = 0;
        #pragma unroll
        for (int e = 0; e < N_EXP; ++e) { offsets[e] = acc; acc += counts[e]; }
    }
}

// ---------------------------------------------------------------------------
// Merged scatter + cvtW1: bid < SCATB -> scatter (LDS-free passenger),
// else convert W1 [E][1024][4096] -> W1t [E][4096][1024].
// ---------------------------------------------------------------------------
__global__ __launch_bounds__(256) void k_scatter_cvt(
    const int* __restrict__ tok_e, const float* __restrict__ tok_g,
    const int* __restrict__ offsets, int* __restrict__ cursor,
    int* __restrict__ list_tok, float* __restrict__ list_gate,
    const float* __restrict__ W1, u16* __restrict__ W1t)
{
    __shared__ __align__(16) u16 s[128 * 134];

    if (blockIdx.x >= SCATB) {
        const int cb = blockIdx.x - SCATB;     // W1 cvt grid: (32, 8, 8)
        cvt_tile(W1, W1t, D_MODEL, HID, cb & 31, (cb >> 5) & 7, cb >> 8, s);
        return;
    }

    const int gid = blockIdx.x * 256 + threadIdx.x;
    if (gid >= NPAIR) return;
    const int e = tok_e[gid];
    const int p = atomicAdd(&cursor[e], 1);
    const int slot = offsets[e] + p;
    list_tok[slot]  = gid >> 1;
    list_gate[slot] = tok_g[gid];
}

// ---------------------------------------------------------------------------
// Merged ffn1 + (optional) cvtW2. (r13-validated, verbatim)
// bid < FFN1B: grouped MFMA GEMM1; else convert W2 -> W2t.
// ---------------------------------------------------------------------------
__global__ __launch_bounds__(256, 4) void k_ffn1m(
    const u16* __restrict__ xb,     // [T][1024]
    const u16* __restrict__ W1t,    // [E][4096][1024]
    const float* __restrict__ b1,
    const int* __restrict__ counts, const int* __restrict__ offsets,
    const int* __restrict__ list_tok,
    u16* __restrict__ H,            // [NPAIR][4096]
    const float* __restrict__ W2, u16* __restrict__ W2t)
{
    __shared__ __align__(16) char smem[34816];

    if (blockIdx.x >= FFN1B) {
        // W2 cvt grid: (D_MODEL/128=8, HID/128=32, 8)
        const int cb = blockIdx.x - FFN1B;
        cvt_tile(W2, W2t, HID, D_MODEL, cb & 7, (cb >> 3) & 31, cb >> 8,
                 (u16*)smem);
        return;
    }

    u16* SA   = (u16*)smem;              // 2 x 4096 u16 = 16 KB
    u16* SB   = (u16*)(smem + 16384);    // 16 KB
    int* stok = (int*)(smem + 32768);    // 512 B

    const int bid = blockIdx.x;
    const int n_t = (bid & 7) | (((bid >> 3) & 3) << 3);   // 0..31, n_t&7 = XCD
    const int wsl = bid >> 5;

    int e, m_t;
    if (!work_map(counts, wsl, e, m_t)) return;
    const int cnt  = counts[e];
    const int base = offsets[e];
    const int m0   = m_t * 128;
    const int n0   = n_t * 128;
    const u16* __restrict__ Be = W1t + (size_t)e * (HID * D_MODEL);

    const int tid = threadIdx.x;
    if (tid < 128) stok[tid] = list_tok[base + min(m0 + tid, cnt - 1)];
    __syncthreads();

    int ar0, ak0, ar1, ak1;
    chunk_map(tid, ar0, ak0);
    chunk_map(tid + 256, ar1, ak1);
    const u16* Asrc0 = xb + (size_t)stok[ar0] * D_MODEL + ak0;
    const u16* Asrc1 = xb + (size_t)stok[ar1] * D_MODEL + ak1;
    const u16* Bsrc0 = Be + (size_t)(n0 + ar0) * D_MODEL + ak0;
    const u16* Bsrc1 = Be + (size_t)(n0 + ar1) * D_MODEL + ak1;

    const int lane = tid & 63, lr = lane & 15, hk = lane >> 4;
    const int w = tid >> 6, wm = w >> 1, wn = w & 1;
    const int colb  = ((((lr & 1) << 2) + hk) ^ (lr >> 1)) << 4;
    const int baseA = ((wm * 32 + (lr >> 1)) << 7) + colb;
    const int baseB = ((wn * 32 + (lr >> 1)) << 7) + colb;

    float bias[4];
    #pragma unroll
    for (int j = 0; j < 4; ++j) bias[j] = b1[(size_t)e * HID + n0 + wn * 64 + j * 16 + lr];

    f32x4 acc[4][4] = {};

    auto STAGE = [&](int s, int t) {
        const int kt = t * 32;
        char* Ab = (char*)SA + s * 8192;
        char* Bb = (char*)SB + s * 8192;
        glds16(Asrc0 + kt, Ab + tid * 16);
        glds16(Asrc1 + kt, Ab + (tid + 256) * 16);
        glds16(Bsrc0 + kt, Bb + tid * 16);
        glds16(Bsrc1 + kt, Bb + (tid + 256) * 16);
    };
    auto COMPUTE = [&](int s) {
        const char* Ab = (const char*)SA + s * 8192;
        const char* Bb = (const char*)SB + s * 8192;
        bf16x8 a[4], b[4];
        #pragma unroll
        for (int i = 0; i < 4; ++i) a[i] = *(const bf16x8*)(Ab + baseA + i * 1024);
        #pragma unroll
        for (int j = 0; j < 4; ++j) b[j] = *(const bf16x8*)(Bb + baseB + j * 1024);
        #pragma unroll
        for (int i = 0; i < 4; ++i)
            #pragma unroll
            for (int j = 0; j < 4; ++j)
                acc[i][j] = __builtin_amdgcn_mfma_f32_16x16x32_bf16(a[i], b[j], acc[i][j], 0, 0, 0);
    };

    const int NT = D_MODEL / 32;                // 32
    STAGE(0, 0);
    STAGE(1, 1);
    for (int t = 0; t < NT; ++t) {
        if (t < NT - 1) { asm volatile("s_waitcnt vmcnt(4)" ::: "memory"); }
        else            { asm volatile("s_waitcnt vmcnt(0)" ::: "memory"); }
        __builtin_amdgcn_s_barrier();
        __builtin_amdgcn_sched_barrier(0);
        COMPUTE(t & 1);
        __builtin_amdgcn_sched_barrier(0);
        __builtin_amdgcn_s_barrier();           // all reads of buf (t&1) done
        if (t + 2 < NT) STAGE(t & 1, t + 2);    // overwrite it for t+2
    }

    #pragma unroll
    for (int i = 0; i < 4; ++i) {
        #pragma unroll
        for (int g = 0; g < 4; ++g) {
            const int m = m0 + wm * 64 + i * 16 + hk * 4 + g;
            if (m < cnt) {
                u16* dst = H + (size_t)(base + m) * HID + n0 + wn * 64 + lr;
                #pragma unroll
                for (int j = 0; j < 4; ++j)
                    dst[j * 16] = f2bf(fmaxf(acc[i][j][g] + bias[j], 0.f));
            }
        }
    }
}

// ---------------------------------------------------------------------------
// Grouped MFMA GEMM2: out += gate*(H @ W2t^T + b2).  (r6-validated, verbatim)
// ---------------------------------------------------------------------------
__global__ __launch_bounds__(256, 4) void k_ffn2(
    const u16* __restrict__ Hb,     // [NPAIR][4096]
    const u16* __restrict__ W2t,    // [E][1024][4096]
    const float* __restrict__ b2,
    const int* __restrict__ counts, const int* __restrict__ offsets,
    const int* __restrict__ list_tok, const float* __restrict__ list_gate,
    float* __restrict__ out)
{
    const int bid = blockIdx.x;
    const int n_t = bid & 7;
    const int wsl = bid >> 3;

    int e, m_t;
    if (!work_map(counts, wsl, e, m_t)) return;
    const int cnt  = counts[e];
    const int base = offsets[e];
    const int m0   = m_t * 128;
    const int n0   = n_t * 128;
    const u16* __restrict__ Be = W2t + (size_t)e * (D_MODEL * HID);

    __shared__ __align__(16) u16 SA[2 * 4096];
    __shared__ __align__(16) u16 SB[2 * 4096];
    __shared__ int   s_tok[128];
    __shared__ float s_gate[128];

    const int tid = threadIdx.x;
    if (tid < 128) {
        const int sl = base + min(m0 + tid, cnt - 1);
        s_tok[tid]  = list_tok[sl];
        s_gate[tid] = list_gate[sl];
    }
    __syncthreads();

    int ar0, ak0, ar1, ak1;
    chunk_map(tid, ar0, ak0);
    chunk_map(tid + 256, ar1, ak1);
    const u16* Asrc0 = Hb + (size_t)(base + min(m0 + ar0, cnt - 1)) * HID + ak0;
    const u16* Asrc1 = Hb + (size_t)(base + min(m0 + ar1, cnt - 1)) * HID + ak1;
    const u16* Bsrc0 = Be + (size_t)(n0 + ar0) * HID + ak0;
    const u16* Bsrc1 = Be + (size_t)(n0 + ar1) * HID + ak1;

    const int lane = tid & 63, lr = lane & 15, hk = lane >> 4;
    const int w = tid >> 6, wm = w >> 1, wn = w & 1;
    const int colb  = ((((lr & 1) << 2) + hk) ^ (lr >> 1)) << 4;
    const int baseA = ((wm * 32 + (lr >> 1)) << 7) + colb;
    const int baseB = ((wn * 32 + (lr >> 1)) << 7) + colb;

    float bias[4];
    #pragma unroll
    for (int j = 0; j < 4; ++j) bias[j] = b2[(size_t)e * D_MODEL + n0 + wn * 64 + j * 16 + lr];

    f32x4 acc[4][4] = {};

    auto STAGE = [&](int s, int t) {
        const int kt = t * 32;
        char* Ab = (char*)SA + s * 8192;
        char* Bb = (char*)SB + s * 8192;
        glds16(Asrc0 + kt, Ab + tid * 16);
        glds16(Asrc1 + kt, Ab + (tid + 256) * 16);
        glds16(Bsrc0 + kt, Bb + tid * 16);
        glds16(Bsrc1 + kt, Bb + (tid + 256) * 16);
    };
    auto COMPUTE = [&](int s) {
        const char* Ab = (const char*)SA + s * 8192;
        const char* Bb = (const char*)SB + s * 8192;
        bf16x8 a[4], b[4];
        #pragma unroll
        for (int i = 0; i < 4; ++i) a[i] = *(const bf16x8*)(Ab + baseA + i * 1024);
        #pragma unroll
        for (int j = 0; j < 4; ++j) b[j] = *(const bf16x8*)(Bb + baseB + j * 1024);
        #pragma unroll
        for (int i = 0; i < 4; ++i)
            #pragma unroll
            for (int j = 0; j < 4; ++j)
                acc[i][j] = __builtin_amdgcn_mfma_f32_16x16x32_bf16(a[i], b[j], acc[i][j], 0, 0, 0);
    };

    const int NT = HID / 32;                    // 128
    STAGE(0, 0);
    STAGE(1, 1);
    for (int t = 0; t < NT; ++t) {
        if (t < NT - 1) { asm volatile("s_waitcnt vmcnt(4)" ::: "memory"); }
        else            { asm volatile("s_waitcnt vmcnt(0)" ::: "memory"); }
        __builtin_amdgcn_s_barrier();
        __builtin_amdgcn_sched_barrier(0);
        COMPUTE(t & 1);
        __builtin_amdgcn_sched_barrier(0);
        __builtin_amdgcn_s_barrier();
        if (t + 2 < NT) STAGE(t & 1, t + 2);
    }

    #pragma unroll
    for (int i = 0; i < 4; ++i) {
        #pragma unroll
        for (int g = 0; g < 4; ++g) {
            const int m = m0 + wm * 64 + i * 16 + hk * 4 + g;
            if (m < cnt) {
                const int   mm = m - m0;
                const int   tk = s_tok[mm];
                const float gt = s_gate[mm];
                float* dst = out + (size_t)tk * D_MODEL + n0 + wn * 64 + lr;
                #pragma unroll
                for (int j = 0; j < 4; ++j)
                    unsafeAtomicAdd(dst + j * 16, gt * (acc[i][j][g] + bias[j]));
            }
        }
    }
}

// ---------------------------------------------------------------------------
extern "C" void kernel_launch(void* const* d_in, const int* in_sizes, int n_in,
                              void* d_out, int out_size, void* d_ws, size_t ws_size,
                              hipStream_t stream)
{
    const float* x     = (const float*)d_in[0];
    const float* noise = (const float*)d_in[1];
    const float* Wr    = (const float*)d_in[2];
    const float* br    = (const float*)d_in[3];
    const float* Wn    = (const float*)d_in[4];
    const float* bn    = (const float*)d_in[5];
    const float* W1    = (const float*)d_in[6];
    const float* b1    = (const float*)d_in[7];
    const float* W2    = (const float*)d_in[8];
    const float* b2    = (const float*)d_in[9];
    float* out = (float*)d_out;

    char* ws = (char*)d_ws;
    int*   counts    = (int*)(ws + WS_COUNTS);
    int*   cursor    = (int*)(ws + WS_CURSOR);
    int*   offsets   = (int*)(ws + WS_OFFSETS);
    int*   tok_e     = (int*)(ws + WS_TOKE);
    float* tok_g     = (float*)(ws + WS_TOKG);
    int*   list_tok  = (int*)(ws + WS_LTOK);
    float* list_gate = (float*)(ws + WS_LGATE);
    u16*   xb        = (u16*)(ws + WS_XB);
    u16*   W1b       = (u16*)(ws + WS_WB);
    u16*   Hb        = (u16*)(ws + WS_H);

    const bool big = (ws_size >= WS_NEEDED);
    u16* W2b = big ? (u16*)(ws + WS_W2) : W1b;

    hipMemsetAsync(ws, 0, 128, stream);
    hipMemsetAsync(d_out, 0, (size_t)out_size * sizeof(float), stream);

    // router standalone (small LDS -> full occupancy)
    k_router<<<T_TOK, 256, 0, stream>>>(x, noise, Wr, br, Wn, bn,
                                        counts, tok_e, tok_g, xb);
    k_prefix<<<1, 64, 0, stream>>>(counts, offsets);

    // scatter (32 blocks) rides along with cvtW1 (2048 blocks)
    k_scatter_cvt<<<SCATB + CVT1B, 256, 0, stream>>>(
        tok_e, tok_g, offsets, cursor, list_tok, list_gate, W1, W1b);

    if (big) {
        // ffn1 (2304 blocks) + cvtW2 (2048 blocks) co-scheduled (r13 win)
        k_ffn1m<<<FFN1B + CVT2B, 256, 0, stream>>>(
            xb, W1b, b1, counts, offsets, list_tok, Hb, W2, W2b);
    } else {
        k_ffn1m<<<FFN1B, 256, 0, stream>>>(
            xb, W1b, b1, counts, offsets, list_tok, Hb, W2, W2b);
        k_cvtT<<<dim3(D_MODEL / 128, HID / 128, N_EXP), 256, 0, stream>>>(
            W2, W2b, HID, D_MODEL);
    }

    k_ffn2<<<8 * WSLOTS, 256, 0, stream>>>(Hb, W2b, b2, counts, offsets,
                                           list_tok, list_gate, out);
}

// Round 15
// 434.623 us; speedup vs baseline: 1.0022x; 1.0022x over previous
//
#include <hip/hip_runtime.h>
#include <hip/hip_bf16.h>
#include <cstdint>
#include <cstddef>

#define D_MODEL 1024
#define N_EXP   8
#define HID     4096
#define T_TOK   4096          // B*S
#define NPAIR   (T_TOK * 2)   // top-2
#define WSLOTS  72            // max m-tiles total: 8192/128 + 7 = 71
#define FFN1B   (32 * WSLOTS) // 2304 ffn1 blocks
#define CVT1B   4096          // W1 cvt blocks: 8e x 16(by) x 32(bx)
#define CVT2B   4096          // W2 cvt blocks: 8e x 64(by) x 8(bx)

// ---------------- workspace layout (bytes) ----------------
#define WS_COUNTS   0
#define WS_CURSOR   32
#define WS_OFFSETS  64
#define WS_TOKE     128                       // tok_e[T][2] int
#define WS_TOKG     32896                     // tok_g[T][2] float
#define WS_LTOK     65664                     // list_tok[NPAIR] int
#define WS_LGATE    98432                     // list_gate[NPAIR] float
#define WS_XB       131328                    // xb[T][1024] bf16        (8 MB)
#define WS_WB       (WS_XB + 8388608)         // W1t bf16                (64 MB)
#define WS_H        (WS_WB + 67108864)        // H[NPAIR][4096] bf16     (64 MB)
#define WS_W2       (WS_H + 67108864)         // W2t bf16 (if ws allows) (64 MB)
#define WS_NEEDED   ((size_t)WS_W2 + 67108864)

typedef __attribute__((ext_vector_type(8))) short bf16x8;
typedef __attribute__((ext_vector_type(4))) float f32x4;
typedef __attribute__((ext_vector_type(8))) unsigned short u16x8;
typedef unsigned short u16;

__device__ __forceinline__ u16 f2bf(float f) {
    unsigned u = __float_as_uint(f);
    u += 0x7FFFu + ((u >> 16) & 1u);          // RNE
    return (u16)(u >> 16);
}

__device__ __forceinline__ void glds16(const void* g, void* l) {
    __builtin_amdgcn_global_load_lds(
        (const __attribute__((address_space(1))) void*)g,
        (__attribute__((address_space(3))) void*)l, 16, 0, 0);
}

// Swizzled-stage chunk map (validated r3/r6: conflicts 0, bit-exact output).
__device__ __forceinline__ void chunk_map(int c, int& row, int& kc) {
    const int line = c >> 3, c8 = c & 7, u = c8 ^ (line & 7);
    row = line * 2 + (u >> 2);
    kc  = (u & 3) * 8;                        // ushort offset in 32-wide K window
}

// compact worklist: slot w -> (expert, m_tile). uniform per block.
__device__ __forceinline__ bool work_map(const int* counts, int w,
                                         int& e, int& m_t) {
    int tot = 0; e = -1; m_t = 0;
    #pragma unroll
    for (int i = 0; i < N_EXP; ++i) {
        const int tl = (counts[i] + 127) >> 7;
        if (e < 0 && w < tot + tl) { e = i; m_t = w - tot; }
        tot += tl;
    }
    return e >= 0;
}

// ---------------------------------------------------------------------------
// Transpose+convert tile v4: f32 [R][C] -> bf16 [C][R], tile 64 rows x 128
// cols. LDS u16[64][136] = 17408 B (8 blocks/CU). Loads batched 8-deep into
// registers before convert (latency tolerance); pad 136 -> row-gather (8 rows,
// stride 136) hits banks 4j mod 32 = conflict-free; writes 128 B runs.
// ---------------------------------------------------------------------------
__device__ __forceinline__ void cvt_tile64(
    const float* __restrict__ in, u16* __restrict__ outp, int R, int C,
    int bx, int by, int bz, u16* s)
{
    const size_t esz = (size_t)R * C;
    const float* ine = in + (size_t)bz * esz;
    u16* oute = outp + (size_t)bz * esz;
    const int c0 = bx * 128, r0 = by * 64;
    const int tid = threadIdx.x;

    float4 v[8];
    #pragma unroll
    for (int p = 0; p < 8; ++p) {
        const int idx = p * 256 + tid;
        const int row = idx >> 5, c4 = (idx & 31) * 4;
        v[p] = *(const float4*)(ine + (size_t)(r0 + row) * C + c0 + c4);
    }
    #pragma unroll
    for (int p = 0; p < 8; ++p) {
        const int idx = p * 256 + tid;
        const int row = idx >> 5, c4 = (idx & 31) * 4;
        ushort2 lo, hi;
        lo.x = f2bf(v[p].x); lo.y = f2bf(v[p].y);
        hi.x = f2bf(v[p].z); hi.y = f2bf(v[p].w);
        *(ushort2*)(s + row * 136 + c4)     = lo;
        *(ushort2*)(s + row * 136 + c4 + 2) = hi;
    }
    __syncthreads();

    #pragma unroll
    for (int p = 0; p < 4; ++p) {
        const int idx = p * 256 + tid;
        const int col = idx >> 3, r8 = (idx & 7) * 8;
        u16x8 o;
        #pragma unroll
        for (int i = 0; i < 8; ++i) o[i] = s[(r8 + i) * 136 + col];
        *(u16x8*)(oute + (size_t)(c0 + col) * R + r0 + r8) = o;
    }
    __syncthreads();   // safe reuse if ever looped
}

// standalone cvt kernel (fallback path): grid (C/128, R/64, E)
__global__ __launch_bounds__(256) void k_cvtT(
    const float* __restrict__ in, u16* __restrict__ outp, int R, int C)
{
    __shared__ __align__(16) u16 s[64 * 136];
    cvt_tile64(in, outp, R, C, blockIdx.x, blockIdx.y, blockIdx.z, s);
}

// ---------------------------------------------------------------------------
// Merged cvtW1 + router. bid < CVT1B: convert W1 [E][1024][4096] -> W1t
// (17.4 KB LDS -> 8 blocks/CU, unlike r13's 34.8 KB). Else router token.
// ---------------------------------------------------------------------------
__global__ __launch_bounds__(256) void k_router_cvt(
    const float* __restrict__ x, const float* __restrict__ noise,
    const float* __restrict__ Wr, const float* __restrict__ br,
    const float* __restrict__ Wn, const float* __restrict__ bn,
    int* __restrict__ counts, int* __restrict__ tok_e, float* __restrict__ tok_g,
    u16* __restrict__ xb,
    const float* __restrict__ W1, u16* __restrict__ W1t)
{
    __shared__ __align__(16) char smem[17408];

    if (blockIdx.x < CVT1B) {
        // W1 cvt grid: bx in [0,32) (cols of 4096), by in [0,16) (rows of 1024)
        const int cb = blockIdx.x;
        cvt_tile64(W1, W1t, D_MODEL, HID, cb & 31, (cb >> 5) & 15, cb >> 9,
                   (u16*)smem);
        return;
    }

    float* sR = (float*)smem;            // 256 floats
    float* sN = (float*)(smem + 1024);   // 256 floats
    float* lg = (float*)(smem + 2048);   // 8 floats

    const int t   = blockIdx.x - CVT1B;
    const int tid = threadIdx.x;
    const int e   = tid & 7;
    const int g   = tid >> 3;
    const float* xr = x + (size_t)t * D_MODEL;

    {
        const float4 v4 = *(const float4*)(xr + tid * 4);
        ushort4 o;
        o.x = f2bf(v4.x); o.y = f2bf(v4.y); o.z = f2bf(v4.z); o.w = f2bf(v4.w);
        *(ushort4*)(xb + (size_t)t * D_MODEL + tid * 4) = o;
    }

    float ar = 0.f, an = 0.f;
    const int ibase = g * 32;
    #pragma unroll 8
    for (int j = 0; j < 32; ++j) {
        const int i = ibase + j;
        const float xv = xr[i];
        ar = fmaf(xv, Wr[i * 8 + e], ar);
        an = fmaf(xv, Wn[i * 8 + e], an);
    }

    sR[tid] = ar; sN[tid] = an;
    __syncthreads();
    for (int off = 128; off >= 8; off >>= 1) {
        if (tid < off) { sR[tid] += sR[tid + off]; sN[tid] += sN[tid + off]; }
        __syncthreads();
    }

    if (tid < 8) {
        const float z  = sN[tid] + bn[tid];
        const float sp = fmaxf(z, 0.f) + log1pf(expf(-fabsf(z)));
        lg[tid] = sR[tid] + br[tid] + sp * noise[t * 8 + tid];
    }
    __syncthreads();

    if (tid == 0) {
        float v0 = -INFINITY, v1 = -INFINITY;
        int   i0 = 0,         i1 = 0;
        #pragma unroll
        for (int ee = 0; ee < 8; ++ee) {
            const float v = lg[ee];
            if (v > v0)      { v1 = v0; i1 = i0; v0 = v; i0 = ee; }
            else if (v > v1) { v1 = v;  i1 = ee; }
        }
        const float ew  = expf(v1 - v0);
        const float inv = 1.f / (1.f + ew);
        tok_e[t * 2 + 0] = i0;
        tok_e[t * 2 + 1] = i1;
        tok_g[t * 2 + 0] = inv;
        tok_g[t * 2 + 1] = ew * inv;
        atomicAdd(&counts[i0], 1);
        atomicAdd(&counts[i1], 1);
    }
}

__global__ void k_prefix(const int* __restrict__ counts, int* __restrict__ offsets)
{
    if (threadIdx.x == 0 && blockIdx.x == 0) {
        int acc = 0;
        #pragma unroll
        for (int e = 0; e < N_EXP; ++e) { offsets[e] = acc; acc += counts[e]; }
    }
}

__global__ __launch_bounds__(256) void k_scatter(
    const int* __restrict__ tok_e, const float* __restrict__ tok_g,
    const int* __restrict__ offsets, int* __restrict__ cursor,
    int* __restrict__ list_tok, float* __restrict__ list_gate)
{
    const int gid = blockIdx.x * 256 + threadIdx.x;
    if (gid >= NPAIR) return;
    const int e = tok_e[gid];
    const int p = atomicAdd(&cursor[e], 1);
    const int slot = offsets[e] + p;
    list_tok[slot]  = gid >> 1;
    list_gate[slot] = tok_g[gid];
}

// ---------------------------------------------------------------------------
// Merged ffn1 + (optional) cvtW2. (r13-validated host body, verbatim)
// bid < FFN1B: grouped MFMA GEMM1; else convert W2 -> W2t (v4 tiles).
// ---------------------------------------------------------------------------
__global__ __launch_bounds__(256, 4) void k_ffn1m(
    const u16* __restrict__ xb,     // [T][1024]
    const u16* __restrict__ W1t,    // [E][4096][1024]
    const float* __restrict__ b1,
    const int* __restrict__ counts, const int* __restrict__ offsets,
    const int* __restrict__ list_tok,
    u16* __restrict__ H,            // [NPAIR][4096]
    const float* __restrict__ W2, u16* __restrict__ W2t)
{
    __shared__ __align__(16) char smem[33280];

    if (blockIdx.x >= FFN1B) {
        // W2 cvt grid: bx in [0,8) (cols of 1024), by in [0,64) (rows of 4096)
        const int cb = blockIdx.x - FFN1B;
        cvt_tile64(W2, W2t, HID, D_MODEL, cb & 7, (cb >> 3) & 63, cb >> 9,
                   (u16*)smem);
        return;
    }

    u16* SA   = (u16*)smem;              // 2 x 4096 u16 = 16 KB
    u16* SB   = (u16*)(smem + 16384);    // 16 KB
    int* stok = (int*)(smem + 32768);    // 512 B

    const int bid = blockIdx.x;
    const int n_t = (bid & 7) | (((bid >> 3) & 3) << 3);   // 0..31, n_t&7 = XCD
    const int wsl = bid >> 5;

    int e, m_t;
    if (!work_map(counts, wsl, e, m_t)) return;
    const int cnt  = counts[e];
    const int base = offsets[e];
    const int m0   = m_t * 128;
    const int n0   = n_t * 128;
    const u16* __restrict__ Be = W1t + (size_t)e * (HID * D_MODEL);

    const int tid = threadIdx.x;
    if (tid < 128) stok[tid] = list_tok[base + min(m0 + tid, cnt - 1)];
    __syncthreads();

    int ar0, ak0, ar1, ak1;
    chunk_map(tid, ar0, ak0);
    chunk_map(tid + 256, ar1, ak1);
    const u16* Asrc0 = xb + (size_t)stok[ar0] * D_MODEL + ak0;
    const u16* Asrc1 = xb + (size_t)stok[ar1] * D_MODEL + ak1;
    const u16* Bsrc0 = Be + (size_t)(n0 + ar0) * D_MODEL + ak0;
    const u16* Bsrc1 = Be + (size_t)(n0 + ar1) * D_MODEL + ak1;

    const int lane = tid & 63, lr = lane & 15, hk = lane >> 4;
    const int w = tid >> 6, wm = w >> 1, wn = w & 1;
    const int colb  = ((((lr & 1) << 2) + hk) ^ (lr >> 1)) << 4;
    const int baseA = ((wm * 32 + (lr >> 1)) << 7) + colb;
    const int baseB = ((wn * 32 + (lr >> 1)) << 7) + colb;

    float bias[4];
    #pragma unroll
    for (int j = 0; j < 4; ++j) bias[j] = b1[(size_t)e * HID + n0 + wn * 64 + j * 16 + lr];

    f32x4 acc[4][4] = {};

    auto STAGE = [&](int s, int t) {
        const int kt = t * 32;
        char* Ab = (char*)SA + s * 8192;
        char* Bb = (char*)SB + s * 8192;
        glds16(Asrc0 + kt, Ab + tid * 16);
        glds16(Asrc1 + kt, Ab + (tid + 256) * 16);
        glds16(Bsrc0 + kt, Bb + tid * 16);
        glds16(Bsrc1 + kt, Bb + (tid + 256) * 16);
    };
    auto COMPUTE = [&](int s) {
        const char* Ab = (const char*)SA + s * 8192;
        const char* Bb = (const char*)SB + s * 8192;
        bf16x8 a[4], b[4];
        #pragma unroll
        for (int i = 0; i < 4; ++i) a[i] = *(const bf16x8*)(Ab + baseA + i * 1024);
        #pragma unroll
        for (int j = 0; j < 4; ++j) b[j] = *(const bf16x8*)(Bb + baseB + j * 1024);
        #pragma unroll
        for (int i = 0; i < 4; ++i)
            #pragma unroll
            for (int j = 0; j < 4; ++j)
                acc[i][j] = __builtin_amdgcn_mfma_f32_16x16x32_bf16(a[i], b[j], acc[i][j], 0, 0, 0);
    };

    const int NT = D_MODEL / 32;                // 32
    STAGE(0, 0);
    STAGE(1, 1);
    for (int t = 0; t < NT; ++t) {
        if (t < NT - 1) { asm volatile("s_waitcnt vmcnt(4)" ::: "memory"); }
        else            { asm volatile("s_waitcnt vmcnt(0)" ::: "memory"); }
        __builtin_amdgcn_s_barrier();
        __builtin_amdgcn_sched_barrier(0);
        COMPUTE(t & 1);
        __builtin_amdgcn_sched_barrier(0);
        __builtin_amdgcn_s_barrier();           // all reads of buf (t&1) done
        if (t + 2 < NT) STAGE(t & 1, t + 2);    // overwrite it for t+2
    }

    #pragma unroll
    for (int i = 0; i < 4; ++i) {
        #pragma unroll
        for (int g = 0; g < 4; ++g) {
            const int m = m0 + wm * 64 + i * 16 + hk * 4 + g;
            if (m < cnt) {
                u16* dst = H + (size_t)(base + m) * HID + n0 + wn * 64 + lr;
                #pragma unroll
                for (int j = 0; j < 4; ++j)
                    dst[j * 16] = f2bf(fmaxf(acc[i][j][g] + bias[j], 0.f));
            }
        }
    }
}

// ---------------------------------------------------------------------------
// Grouped MFMA GEMM2: out += gate*(H @ W2t^T + b2).  (r6-validated, verbatim)
// ---------------------------------------------------------------------------
__global__ __launch_bounds__(256, 4) void k_ffn2(
    const u16* __restrict__ Hb,     // [NPAIR][4096]
    const u16* __restrict__ W2t,    // [E][1024][4096]
    const float* __restrict__ b2,
    const int* __restrict__ counts, const int* __restrict__ offsets,
    const int* __restrict__ list_tok, const float* __restrict__ list_gate,
    float* __restrict__ out)
{
    const int bid = blockIdx.x;
    const int n_t = bid & 7;
    const int wsl = bid >> 3;

    int e, m_t;
    if (!work_map(counts, wsl, e, m_t)) return;
    const int cnt  = counts[e];
    const int base = offsets[e];
    const int m0   = m_t * 128;
    const int n0   = n_t * 128;
    const u16* __restrict__ Be = W2t + (size_t)e * (D_MODEL * HID);

    __shared__ __align__(16) u16 SA[2 * 4096];
    __shared__ __align__(16) u16 SB[2 * 4096];
    __shared__ int   s_tok[128];
    __shared__ float s_gate[128];

    const int tid = threadIdx.x;
    if (tid < 128) {
        const int sl = base + min(m0 + tid, cnt - 1);
        s_tok[tid]  = list_tok[sl];
        s_gate[tid] = list_gate[sl];
    }
    __syncthreads();

    int ar0, ak0, ar1, ak1;
    chunk_map(tid, ar0, ak0);
    chunk_map(tid + 256, ar1, ak1);
    const u16* Asrc0 = Hb + (size_t)(base + min(m0 + ar0, cnt - 1)) * HID + ak0;
    const u16* Asrc1 = Hb + (size_t)(base + min(m0 + ar1, cnt - 1)) * HID + ak1;
    const u16* Bsrc0 = Be + (size_t)(n0 + ar0) * HID + ak0;
    const u16* Bsrc1 = Be + (size_t)(n0 + ar1) * HID + ak1;

    const int lane = tid & 63, lr = lane & 15, hk = lane >> 4;
    const int w = tid >> 6, wm = w >> 1, wn = w & 1;
    const int colb  = ((((lr & 1) << 2) + hk) ^ (lr >> 1)) << 4;
    const int baseA = ((wm * 32 + (lr >> 1)) << 7) + colb;
    const int baseB = ((wn * 32 + (lr >> 1)) << 7) + colb;

    float bias[4];
    #pragma unroll
    for (int j = 0; j < 4; ++j) bias[j] = b2[(size_t)e * D_MODEL + n0 + wn * 64 + j * 16 + lr];

    f32x4 acc[4][4] = {};

    auto STAGE = [&](int s, int t) {
        const int kt = t * 32;
        char* Ab = (char*)SA + s * 8192;
        char* Bb = (char*)SB + s * 8192;
        glds16(Asrc0 + kt, Ab + tid * 16);
        glds16(Asrc1 + kt, Ab + (tid + 256) * 16);
        glds16(Bsrc0 + kt, Bb + tid * 16);
        glds16(Bsrc1 + kt, Bb + (tid + 256) * 16);
    };
    auto COMPUTE = [&](int s) {
        const char* Ab = (const char*)SA + s * 8192;
        const char* Bb = (const char*)SB + s * 8192;
        bf16x8 a[4], b[4];
        #pragma unroll
        for (int i = 0; i < 4; ++i) a[i] = *(const bf16x8*)(Ab + baseA + i * 1024);
        #pragma unroll
        for (int j = 0; j < 4; ++j) b[j] = *(const bf16x8*)(Bb + baseB + j * 1024);
        #pragma unroll
        for (int i = 0; i < 4; ++i)
            #pragma unroll
            for (int j = 0; j < 4; ++j)
                acc[i][j] = __builtin_amdgcn_mfma_f32_16x16x32_bf16(a[i], b[j], acc[i][j], 0, 0, 0);
    };

    const int NT = HID / 32;                    // 128
    STAGE(0, 0);
    STAGE(1, 1);
    for (int t = 0; t < NT; ++t) {
        if (t < NT - 1) { asm volatile("s_waitcnt vmcnt(4)" ::: "memory"); }
        else            { asm volatile("s_waitcnt vmcnt(0)" ::: "memory"); }
        __builtin_amdgcn_s_barrier();
        __builtin_amdgcn_sched_barrier(0);
        COMPUTE(t & 1);
        __builtin_amdgcn_sched_barrier(0);
        __builtin_amdgcn_s_barrier();
        if (t + 2 < NT) STAGE(t & 1, t + 2);
    }

    #pragma unroll
    for (int i = 0; i < 4; ++i) {
        #pragma unroll
        for (int g = 0; g < 4; ++g) {
            const int m = m0 + wm * 64 + i * 16 + hk * 4 + g;
            if (m < cnt) {
                const int   mm = m - m0;
                const int   tk = s_tok[mm];
                const float gt = s_gate[mm];
                float* dst = out + (size_t)tk * D_MODEL + n0 + wn * 64 + lr;
                #pragma unroll
                for (int j = 0; j < 4; ++j)
                    unsafeAtomicAdd(dst + j * 16, gt * (acc[i][j][g] + bias[j]));
            }
        }
    }
}

// ---------------------------------------------------------------------------
extern "C" void kernel_launch(void* const* d_in, const int* in_sizes, int n_in,
                              void* d_out, int out_size, void* d_ws, size_t ws_size,
                              hipStream_t stream)
{
    const float* x     = (const float*)d_in[0];
    const float* noise = (const float*)d_in[1];
    const float* Wr    = (const float*)d_in[2];
    const float* br    = (const float*)d_in[3];
    const float* Wn    = (const float*)d_in[4];
    const float* bn    = (const float*)d_in[5];
    const float* W1    = (const float*)d_in[6];
    const float* b1    = (const float*)d_in[7];
    const float* W2    = (const float*)d_in[8];
    const float* b2    = (const float*)d_in[9];
    float* out = (float*)d_out;

    char* ws = (char*)d_ws;
    int*   counts    = (int*)(ws + WS_COUNTS);
    int*   cursor    = (int*)(ws + WS_CURSOR);
    int*   offsets   = (int*)(ws + WS_OFFSETS);
    int*   tok_e     = (int*)(ws + WS_TOKE);
    float* tok_g     = (float*)(ws + WS_TOKG);
    int*   list_tok  = (int*)(ws + WS_LTOK);
    float* list_gate = (float*)(ws + WS_LGATE);
    u16*   xb        = (u16*)(ws + WS_XB);
    u16*   W1b       = (u16*)(ws + WS_WB);
    u16*   Hb        = (u16*)(ws + WS_H);

    const bool big = (ws_size >= WS_NEEDED);
    u16* W2b = big ? (u16*)(ws + WS_W2) : W1b;

    hipMemsetAsync(ws, 0, 128, stream);
    hipMemsetAsync(d_out, 0, (size_t)out_size * sizeof(float), stream);

    // cvtW1 (4096 blocks, 17.4 KB LDS) + router (4096 blocks) co-scheduled
    k_router_cvt<<<CVT1B + T_TOK, 256, 0, stream>>>(
        x, noise, Wr, br, Wn, bn, counts, tok_e, tok_g, xb, W1, W1b);
    k_prefix<<<1, 64, 0, stream>>>(counts, offsets);
    k_scatter<<<NPAIR / 256, 256, 0, stream>>>(tok_e, tok_g, offsets, cursor,
                                               list_tok, list_gate);

    if (big) {
        // ffn1 (2304 blocks) + cvtW2 (4096 blocks) co-scheduled (r13 win)
        k_ffn1m<<<FFN1B + CVT2B, 256, 0, stream>>>(
            xb, W1b, b1, counts, offsets, list_tok, Hb, W2, W2b);
    } else {
        k_ffn1m<<<FFN1B, 256, 0, stream>>>(
            xb, W1b, b1, counts, offsets, list_tok, Hb, W2, W2b);
        k_cvtT<<<dim3(D_MODEL / 128, HID / 64, N_EXP), 256, 0, stream>>>(
            W2, W2b, HID, D_MODEL);
    }

    k_ffn2<<<8 * WSLOTS, 256, 0, stream>>>(Hb, W2b, b2, counts, offsets,
                                           list_tok, list_gate, out);
}